// Round 18
// baseline (104.789 us; speedup 1.0000x reference)
//
#include <hip/hip_runtime.h>
#include <hip/hip_bf16.h>
#include <stdint.h>
#include <stddef.h>

#define BATCH 4096
#define INF   1024
#define OUTF  1024
#define KDIM  8192            // 1024 in-features * 8 spline bases
#define KS    4               // split-K factor
#define KSL   (KDIM / KS)     // 2048 per slice
#define BK    64
#define NT    (KSL / BK)      // 32 K-tiles per block

typedef __attribute__((ext_vector_type(8)))  short           short8;
typedef __attribute__((ext_vector_type(8)))  unsigned short  ushort8;
typedef __attribute__((ext_vector_type(4)))  float           f32x4;

__device__ constexpr float knot(int j) { return (float)(j - 3) * 0.4f - 1.0f; }

// ---------------------------------------------------------------------------
// Kernel 1: fused prep (r11/r16-identical). Blocks [0,16384): B-spline bases
// (one thread per (b,i), 8 bf16 out). Blocks [16384,20480): weight fp32->bf16.
// ---------------------------------------------------------------------------
__global__ __launch_bounds__(256) void kan_prep(const float* __restrict__ x,
                                                short8* __restrict__ A,
                                                const f32x4* __restrict__ w,
                                                short8* __restrict__ Wb) {
    const int blk = blockIdx.x;
    if (blk < (BATCH * INF) / 256) {
        size_t idx = (size_t)blk * 256 + threadIdx.x;
        float xv = x[idx];

        float b[11];
#pragma unroll
        for (int j = 0; j < 11; ++j)
            b[j] = (xv >= knot(j) && xv < knot(j + 1)) ? 1.0f : 0.0f;

#pragma unroll
        for (int k = 1; k <= 3; ++k) {
#pragma unroll
            for (int j = 0; j + k < 11; ++j) {
                float left  = (xv - knot(j))         * (1.0f / (knot(j + k)     - knot(j)));
                float right = (knot(j + k + 1) - xv) * (1.0f / (knot(j + k + 1) - knot(j + 1)));
                b[j] = left * b[j] + right * b[j + 1];
            }
        }

        union { short8 v; unsigned short u[8]; } pk;
#pragma unroll
        for (int g = 0; g < 8; ++g) {
            __hip_bfloat16 h = __float2bfloat16(b[g]);
            pk.u[g] = *reinterpret_cast<unsigned short*>(&h);
        }
        A[idx] = pk.v;
    } else {
        size_t idx = (size_t)(blk - (BATCH * INF) / 256) * 256 + threadIdx.x;
        f32x4 a = w[idx * 2];
        f32x4 c = w[idx * 2 + 1];
        float t[8] = {a[0], a[1], a[2], a[3], c[0], c[1], c[2], c[3]};
        union { short8 v; unsigned short u[8]; } pk;
#pragma unroll
        for (int g = 0; g < 8; ++g) {
            __hip_bfloat16 h = __float2bfloat16(t[g]);
            pk.u[g] = *reinterpret_cast<unsigned short*>(&h);
        }
        Wb[idx] = pk.v;
    }
}

// ---------------------------------------------------------------------------
// Kernel 2: bf16 GEMM, 128x128 tile, BK=64, split-K=4, SINGLE-buffer LDS
// (32 KiB -> 4 blocks/CU; 4 independent barrier domains cover each other's
// stage-drains, m114). 256 threads = 4 waves (2M x 2N, 64x64/wave — identical
// wave tile / fragment pattern / zero-conflict swizzle as r10/r11/r16).
// m97 2-barrier loop: stage -> vmcnt(0)+barrier -> compute -> barrier.
// mode 0: bf16 split-K partials; mode 1: fp32 atomic fallback.
// ---------------------------------------------------------------------------
__device__ __forceinline__ void gload16(const void* g, void* l) {
    __builtin_amdgcn_global_load_lds((const __attribute__((address_space(1))) void*)g,
                                     (__attribute__((address_space(3))) void*)l,
                                     16, 0, 0);
}

#define MFMA(a, b, c) __builtin_amdgcn_mfma_f32_16x16x32_bf16((a), (b), (c), 0, 0, 0)

__global__ __launch_bounds__(256, 4) void kan_gemm(const __hip_bfloat16* __restrict__ A,
                                                   const __hip_bfloat16* __restrict__ Bt,
                                                   __hip_bfloat16* __restrict__ Pb,
                                                   float* __restrict__ outC,
                                                   int mode) {
    __shared__ __hip_bfloat16 sA[128 * 64];   // 16 KiB
    __shared__ __hip_bfloat16 sB[128 * 64];   // 16 KiB

    const int tid  = threadIdx.x;
    const int orig = blockIdx.x;
    const int sb   = (orig & 7) * 128 + (orig >> 3);  // XCD chunk swizzle (1024%8==0)
    const int bm   = sb >> 5;            // 0..31
    const int bn   = (sb >> 2) & 7;      // 0..7
    const int ks   = sb & 3;             // 0..3
    const int m0   = bm << 7;
    const int n0   = bn << 7;
    const int k0   = ks * KSL;

    // staging: thread t -> rows (t>>3)+r*32, 16B slot (t&7); LDS dest linear.
    // Source col pre-swizzled: LDS[row][s] = G[row][s ^ (row&7)]; (row&7)
    // invariant across r-steps (32 == 0 mod 8).
    const int srow = tid >> 3;                                // 0..31
    const int scol = (((tid & 7) ^ (srow & 7)) << 3);         // elems
    const __hip_bfloat16* gA = A  + (size_t)(m0 + srow) * KDIM + k0 + scol;
    const __hip_bfloat16* gB = Bt + (size_t)(n0 + srow) * KDIM + k0 + scol;
    const int t8 = tid * 8;

#define GLA(kt, r) gload16(gA + (size_t)(kt) * BK + (size_t)((r) * 32) * KDIM, \
                           &sA[(r) * 2048 + t8])
#define GLB(kt, r) gload16(gB + (size_t)(kt) * BK + (size_t)((r) * 32) * KDIM, \
                           &sB[(r) * 2048 + t8])

    // compute: wave w -> rows [(w>>1)*64,+64), cols [(w&1)*64,+64)
    const int w    = tid >> 6;
    const int lane = tid & 63;
    const int wr   = w >> 1;             // 0..1
    const int wc   = w & 1;              // 0..1
    const int lr   = lane & 15;
    const int lk   = lane >> 4;          // 0..3
    const int ar0  = (wr << 6) + lr;     // + fi*16
    const int br0  = (wc << 6) + lr;     // + fj*16
    const int rx   = lr & 7;             // read-side XOR (row&7)

    f32x4 acc[4][4];
#pragma unroll
    for (int i = 0; i < 4; ++i)
#pragma unroll
        for (int j = 0; j < 4; ++j)
            acc[i][j] = (f32x4){0.0f, 0.0f, 0.0f, 0.0f};

#pragma unroll 1
    for (int t = 0; t < NT; ++t) {
        // stage tile t (8 x 16B per thread); safe: all reads of tile t-1
        // completed before the end-of-iteration barrier below.
        GLA(t, 0); GLA(t, 1); GLA(t, 2); GLA(t, 3);
        GLB(t, 0); GLB(t, 1); GLB(t, 2); GLB(t, 3);
        asm volatile("s_waitcnt vmcnt(0)" ::: "memory");
        __builtin_amdgcn_s_barrier();

        // compute: 2 kk steps; per step 8 ds_read_b128 + 16 MFMA(16x16x32).
        // phys slot = (4kk+lk) ^ (lr&7) -> 0 conflicts (r10/r11/r16-measured).
#pragma unroll
        for (int kk = 0; kk < 2; ++kk) {
            const int ph = (((kk << 2) | lk) ^ rx) << 3;   // elem offset in row
            short8 af[4], bf[4];
#pragma unroll
            for (int fi = 0; fi < 4; ++fi)
                af[fi] = *reinterpret_cast<const short8*>(sA + (ar0 + fi * 16) * BK + ph);
#pragma unroll
            for (int fj = 0; fj < 4; ++fj)
                bf[fj] = *reinterpret_cast<const short8*>(sB + (br0 + fj * 16) * BK + ph);
#pragma unroll
            for (int fi = 0; fi < 4; ++fi)
#pragma unroll
                for (int fj = 0; fj < 4; ++fj)
                    acc[fi][fj] = MFMA(af[fi], bf[fj], acc[fi][fj]);
        }

        // all reads of tile t done (consumed by MFMAs above) -> next stage safe
        __builtin_amdgcn_s_barrier();
    }
#undef GLA
#undef GLB

    // --- epilogue: 16x16 C/D layout: col = lane&15, row = (lane>>4)*4 + reg ---
    if (mode == 0) {
        __hip_bfloat16* dst = Pb + (size_t)ks * BATCH * OUTF;
#pragma unroll
        for (int fi = 0; fi < 4; ++fi) {
#pragma unroll
            for (int fj = 0; fj < 4; ++fj) {
                __hip_bfloat16* cp = dst
                    + (size_t)(m0 + (wr << 6) + fi * 16 + lk * 4) * OUTF
                    + (n0 + (wc << 6) + fj * 16 + lr);
#pragma unroll
                for (int r = 0; r < 4; ++r)
                    cp[(size_t)r * OUTF] = __float2bfloat16(acc[fi][fj][r]);
            }
        }
    } else {
#pragma unroll
        for (int fi = 0; fi < 4; ++fi) {
#pragma unroll
            for (int fj = 0; fj < 4; ++fj) {
                float* cp = outC + (size_t)(m0 + (wr << 6) + fi * 16 + lk * 4) * OUTF
                                 + (n0 + (wc << 6) + fj * 16 + lr);
#pragma unroll
                for (int r = 0; r < 4; ++r)
                    atomicAdd(cp + (size_t)r * OUTF, acc[fi][fj][r]);
            }
        }
    }
}

// ---------------------------------------------------------------------------
// Kernel 3: split-K reduce  out = sum of 4 bf16 partials (fp32 accumulate).
// ---------------------------------------------------------------------------
__global__ __launch_bounds__(256) void kan_reduce(const ushort8* __restrict__ Pb,
                                                  f32x4* __restrict__ out) {
    size_t i = (size_t)blockIdx.x * 256 + threadIdx.x;   // per 8 elems
    const size_t stride = (size_t)BATCH * OUTF / 8;
    ushort8 p0 = Pb[i];
    ushort8 p1 = Pb[i + stride];
    ushort8 p2 = Pb[i + 2 * stride];
    ushort8 p3 = Pb[i + 3 * stride];

    f32x4 lo, hi;
#pragma unroll
    for (int e = 0; e < 8; ++e) {
        union { unsigned int u; float f; } c0, c1, c2, c3;
        c0.u = (unsigned int)p0[e] << 16;
        c1.u = (unsigned int)p1[e] << 16;
        c2.u = (unsigned int)p2[e] << 16;
        c3.u = (unsigned int)p3[e] << 16;
        float s = (c0.f + c1.f) + (c2.f + c3.f);
        if (e < 4) lo[e] = s; else hi[e - 4] = s;
    }
    out[i * 2]     = lo;
    out[i * 2 + 1] = hi;
}

// ---------------------------------------------------------------------------
extern "C" void kernel_launch(void* const* d_in, const int* in_sizes, int n_in,
                              void* d_out, int out_size, void* d_ws, size_t ws_size,
                              hipStream_t stream) {
    const float* x = (const float*)d_in[0];       // (4096, 1024) fp32
    const float* w = (const float*)d_in[1];       // (1024, 1024, 8) fp32
    float* out = (float*)d_out;                   // (4096, 1024) fp32

    const size_t offW  = (size_t)BATCH * KDIM * 2;             // Abf: 64 MiB
    const size_t offP  = offW + (size_t)OUTF * KDIM * 2;       // Wbf: +16 MiB
    const size_t needP = offP + (size_t)KS * BATCH * OUTF * 2; // +32 MiB bf16 partials

    __hip_bfloat16* Abf = (__hip_bfloat16*)d_ws;
    __hip_bfloat16* Wbf = (__hip_bfloat16*)((char*)d_ws + offW);
    __hip_bfloat16* Pb  = (__hip_bfloat16*)((char*)d_ws + offP);
    const bool partials = (ws_size >= needP);

    const int prepGrid = (BATCH * INF) / 256 + (OUTF * KDIM / 8) / 256;  // 20480
    kan_prep<<<prepGrid, 256, 0, stream>>>(x, (short8*)Abf, (const f32x4*)w, (short8*)Wbf);

    const int grid = (BATCH / 128) * (OUTF / 128) * KS;     // 1024 -> 4 blocks/CU
    if (partials) {
        kan_gemm<<<grid, 256, 0, stream>>>(Abf, Wbf, Pb, out, 0);
        kan_reduce<<<(BATCH * OUTF / 8) / 256, 256, 0, stream>>>((const ushort8*)Pb, (f32x4*)out);
    } else {
        hipMemsetAsync(out, 0, (size_t)BATCH * OUTF * sizeof(float), stream);
        kan_gemm<<<grid, 256, 0, stream>>>(Abf, Wbf, Pb, out, 1);
    }
}

// Round 19
// 94.313 us; speedup vs baseline: 1.1111x; 1.1111x over previous
//
#include <hip/hip_runtime.h>
#include <hip/hip_bf16.h>
#include <stdint.h>
#include <stddef.h>

#define BATCH 4096
#define INF   1024
#define OUTF  1024
#define KDIM  8192            // 1024 in-features * 8 spline bases
#define KS    4               // split-K factor
#define KSL   (KDIM / KS)     // 2048 per slice
#define BK    64
#define NT    (KSL / BK)      // 32 K-tiles per block

typedef __attribute__((ext_vector_type(8)))  short           short8;
typedef __attribute__((ext_vector_type(8)))  unsigned short  ushort8;
typedef __attribute__((ext_vector_type(4)))  float           f32x4;

__device__ constexpr float knot(int j) { return (float)(j - 3) * 0.4f - 1.0f; }

// ---------------------------------------------------------------------------
// Kernel 1: fused prep. Blocks [0,16384): B-spline bases (one thread per
// (b,i), 8 bf16 out). Blocks [16384,20480): weight fp32 -> bf16.
// Both sides run at the HBM ceiling (~6.1 TB/s for 128 MB total traffic).
// ---------------------------------------------------------------------------
__global__ __launch_bounds__(256) void kan_prep(const float* __restrict__ x,
                                                short8* __restrict__ A,
                                                const f32x4* __restrict__ w,
                                                short8* __restrict__ Wb) {
    const int blk = blockIdx.x;
    if (blk < (BATCH * INF) / 256) {
        size_t idx = (size_t)blk * 256 + threadIdx.x;
        float xv = x[idx];

        float b[11];
#pragma unroll
        for (int j = 0; j < 11; ++j)
            b[j] = (xv >= knot(j) && xv < knot(j + 1)) ? 1.0f : 0.0f;

#pragma unroll
        for (int k = 1; k <= 3; ++k) {
#pragma unroll
            for (int j = 0; j + k < 11; ++j) {
                float left  = (xv - knot(j))         * (1.0f / (knot(j + k)     - knot(j)));
                float right = (knot(j + k + 1) - xv) * (1.0f / (knot(j + k + 1) - knot(j + 1)));
                b[j] = left * b[j] + right * b[j + 1];
            }
        }

        union { short8 v; unsigned short u[8]; } pk;
#pragma unroll
        for (int g = 0; g < 8; ++g) {
            __hip_bfloat16 h = __float2bfloat16(b[g]);
            pk.u[g] = *reinterpret_cast<unsigned short*>(&h);
        }
        A[idx] = pk.v;
    } else {
        size_t idx = (size_t)(blk - (BATCH * INF) / 256) * 256 + threadIdx.x;
        f32x4 a = w[idx * 2];
        f32x4 c = w[idx * 2 + 1];
        float t[8] = {a[0], a[1], a[2], a[3], c[0], c[1], c[2], c[3]};
        union { short8 v; unsigned short u[8]; } pk;
#pragma unroll
        for (int g = 0; g < 8; ++g) {
            __hip_bfloat16 h = __float2bfloat16(t[g]);
            pk.u[g] = *reinterpret_cast<unsigned short*>(&h);
        }
        Wb[idx] = pk.v;
    }
}

// ---------------------------------------------------------------------------
// Kernel 2: bf16 GEMM, 256x128 tile, BK=64, split-K=4, SINGLE-buffer LDS
// (48 KiB -> 2 blocks/CU; cross-block overlap hides stage-wait + barriers,
// m114; 4 blocks/CU thrashes L2 [r18]; A-dbuf mid-iter syncs cost more than
// they hide [r17]). 512 threads = 8 waves (4M x 2N, 64x64/wave),
// mfma_f32_16x16x32_bf16, zero-conflict fragment pattern + both-sides XOR
// swizzle (r10/r11/r16-verified: SQ_LDS_BANK_CONFLICT == 0). m97 2-barrier
// loop: stage -> vmcnt(0)+barrier -> compute -> barrier.
// mode 0: bf16 split-K partials; mode 1: fp32 atomic fallback.
// ---------------------------------------------------------------------------
__device__ __forceinline__ void gload16(const void* g, void* l) {
    __builtin_amdgcn_global_load_lds((const __attribute__((address_space(1))) void*)g,
                                     (__attribute__((address_space(3))) void*)l,
                                     16, 0, 0);
}

#define MFMA(a, b, c) __builtin_amdgcn_mfma_f32_16x16x32_bf16((a), (b), (c), 0, 0, 0)

__global__ __launch_bounds__(512, 4) void kan_gemm(const __hip_bfloat16* __restrict__ A,
                                                   const __hip_bfloat16* __restrict__ Bt,
                                                   __hip_bfloat16* __restrict__ Pb,
                                                   float* __restrict__ outC,
                                                   int mode) {
    __shared__ __hip_bfloat16 sA[256 * 64];   // 32 KiB
    __shared__ __hip_bfloat16 sB[128 * 64];   // 16 KiB

    const int tid  = threadIdx.x;
    const int orig = blockIdx.x;
    const int sb   = (orig & 7) * 64 + (orig >> 3);   // XCD chunk swizzle (512%8==0)
    const int bm   = sb >> 5;            // 0..15
    const int bn   = (sb >> 2) & 7;      // 0..7
    const int ks   = sb & 3;             // 0..3
    const int m0   = bm << 8;
    const int n0   = bn << 7;
    const int k0   = ks * KSL;

    // staging: thread t -> rows (t>>3)+r*64, 16B slot (t&7); LDS dest linear.
    // Source col pre-swizzled: LDS[row][s] = G[row][s ^ (row&7)]; (row&7)
    // invariant across r-steps (64 == 0 mod 8).
    const int srow = tid >> 3;                                // 0..63
    const int scol = (((tid & 7) ^ (srow & 7)) << 3);         // elems
    const __hip_bfloat16* gA = A  + (size_t)(m0 + srow) * KDIM + k0 + scol;
    const __hip_bfloat16* gB = Bt + (size_t)(n0 + srow) * KDIM + k0 + scol;
    const int t8 = tid * 8;

#define GLA(kt, r) gload16(gA + (size_t)(kt) * BK + (size_t)((r) * 64) * KDIM, \
                           &sA[(r) * 4096 + t8])
#define GLB(kt, r) gload16(gB + (size_t)(kt) * BK + (size_t)((r) * 64) * KDIM, \
                           &sB[(r) * 4096 + t8])

    // compute: wave w -> rows [(w>>1)*64,+64), cols [(w&1)*64,+64)
    const int w    = tid >> 6;
    const int lane = tid & 63;
    const int wr   = w >> 1;             // 0..3
    const int wc   = w & 1;              // 0..1
    const int lr   = lane & 15;
    const int lk   = lane >> 4;          // 0..3
    const int ar0  = (wr << 6) + lr;     // + fi*16
    const int br0  = (wc << 6) + lr;     // + fj*16
    const int rx   = lr & 7;             // read-side XOR (row&7)

    f32x4 acc[4][4];
#pragma unroll
    for (int i = 0; i < 4; ++i)
#pragma unroll
        for (int j = 0; j < 4; ++j)
            acc[i][j] = (f32x4){0.0f, 0.0f, 0.0f, 0.0f};

#pragma unroll 1
    for (int t = 0; t < NT; ++t) {
        // stage tile t (6 x 16B per thread); safe: all reads of tile t-1
        // completed before the end-of-iteration barrier below.
        GLA(t, 0); GLA(t, 1); GLA(t, 2); GLA(t, 3);
        GLB(t, 0); GLB(t, 1);
        asm volatile("s_waitcnt vmcnt(0)" ::: "memory");
        __builtin_amdgcn_s_barrier();

        // compute: 2 kk steps; per step 8 ds_read_b128 + 16 MFMA(16x16x32).
        // phys slot = (4kk+lk) ^ (lr&7) -> 0 conflicts (r10/r11/r16-measured).
#pragma unroll
        for (int kk = 0; kk < 2; ++kk) {
            const int ph = (((kk << 2) | lk) ^ rx) << 3;   // elem offset in row
            short8 af[4], bf[4];
#pragma unroll
            for (int fi = 0; fi < 4; ++fi)
                af[fi] = *reinterpret_cast<const short8*>(sA + (ar0 + fi * 16) * BK + ph);
#pragma unroll
            for (int fj = 0; fj < 4; ++fj)
                bf[fj] = *reinterpret_cast<const short8*>(sB + (br0 + fj * 16) * BK + ph);
#pragma unroll
            for (int fi = 0; fi < 4; ++fi)
#pragma unroll
                for (int fj = 0; fj < 4; ++fj)
                    acc[fi][fj] = MFMA(af[fi], bf[fj], acc[fi][fj]);
        }

        // all reads of tile t done (consumed by MFMAs above) -> next stage safe
        __builtin_amdgcn_s_barrier();
    }
#undef GLA
#undef GLB

    // --- epilogue: 16x16 C/D layout: col = lane&15, row = (lane>>4)*4 + reg ---
    if (mode == 0) {
        __hip_bfloat16* dst = Pb + (size_t)ks * BATCH * OUTF;
#pragma unroll
        for (int fi = 0; fi < 4; ++fi) {
#pragma unroll
            for (int fj = 0; fj < 4; ++fj) {
                __hip_bfloat16* cp = dst
                    + (size_t)(m0 + (wr << 6) + fi * 16 + lk * 4) * OUTF
                    + (n0 + (wc << 6) + fj * 16 + lr);
#pragma unroll
                for (int r = 0; r < 4; ++r)
                    cp[(size_t)r * OUTF] = __float2bfloat16(acc[fi][fj][r]);
            }
        }
    } else {
#pragma unroll
        for (int fi = 0; fi < 4; ++fi) {
#pragma unroll
            for (int fj = 0; fj < 4; ++fj) {
                float* cp = outC + (size_t)(m0 + (wr << 6) + fi * 16 + lk * 4) * OUTF
                                 + (n0 + (wc << 6) + fj * 16 + lr);
#pragma unroll
                for (int r = 0; r < 4; ++r)
                    atomicAdd(cp + (size_t)r * OUTF, acc[fi][fj][r]);
            }
        }
    }
}

// ---------------------------------------------------------------------------
// Kernel 3: split-K reduce  out = sum of 4 bf16 partials (fp32 accumulate).
// ---------------------------------------------------------------------------
__global__ __launch_bounds__(256) void kan_reduce(const ushort8* __restrict__ Pb,
                                                  f32x4* __restrict__ out) {
    size_t i = (size_t)blockIdx.x * 256 + threadIdx.x;   // per 8 elems
    const size_t stride = (size_t)BATCH * OUTF / 8;
    ushort8 p0 = Pb[i];
    ushort8 p1 = Pb[i + stride];
    ushort8 p2 = Pb[i + 2 * stride];
    ushort8 p3 = Pb[i + 3 * stride];

    f32x4 lo, hi;
#pragma unroll
    for (int e = 0; e < 8; ++e) {
        union { unsigned int u; float f; } c0, c1, c2, c3;
        c0.u = (unsigned int)p0[e] << 16;
        c1.u = (unsigned int)p1[e] << 16;
        c2.u = (unsigned int)p2[e] << 16;
        c3.u = (unsigned int)p3[e] << 16;
        float s = (c0.f + c1.f) + (c2.f + c3.f);
        if (e < 4) lo[e] = s; else hi[e - 4] = s;
    }
    out[i * 2]     = lo;
    out[i * 2 + 1] = hi;
}

// ---------------------------------------------------------------------------
extern "C" void kernel_launch(void* const* d_in, const int* in_sizes, int n_in,
                              void* d_out, int out_size, void* d_ws, size_t ws_size,
                              hipStream_t stream) {
    const float* x = (const float*)d_in[0];       // (4096, 1024) fp32
    const float* w = (const float*)d_in[1];       // (1024, 1024, 8) fp32
    float* out = (float*)d_out;                   // (4096, 1024) fp32

    const size_t offW  = (size_t)BATCH * KDIM * 2;             // Abf: 64 MiB
    const size_t offP  = offW + (size_t)OUTF * KDIM * 2;       // Wbf: +16 MiB
    const size_t needP = offP + (size_t)KS * BATCH * OUTF * 2; // +32 MiB bf16 partials

    __hip_bfloat16* Abf = (__hip_bfloat16*)d_ws;
    __hip_bfloat16* Wbf = (__hip_bfloat16*)((char*)d_ws + offW);
    __hip_bfloat16* Pb  = (__hip_bfloat16*)((char*)d_ws + offP);
    const bool partials = (ws_size >= needP);

    const int prepGrid = (BATCH * INF) / 256 + (OUTF * KDIM / 8) / 256;  // 20480
    kan_prep<<<prepGrid, 256, 0, stream>>>(x, (short8*)Abf, (const f32x4*)w, (short8*)Wbf);

    const int grid = (BATCH / 256) * (OUTF / 128) * KS;     // 512 -> 2 blocks/CU
    if (partials) {
        kan_gemm<<<grid, 512, 0, stream>>>(Abf, Wbf, Pb, out, 0);
        kan_reduce<<<(BATCH * OUTF / 8) / 256, 256, 0, stream>>>((const ushort8*)Pb, (f32x4*)out);
    } else {
        hipMemsetAsync(out, 0, (size_t)BATCH * OUTF * sizeof(float), stream);
        kan_gemm<<<grid, 512, 0, stream>>>(Abf, Wbf, Pb, out, 1);
    }
}